// Round 1
// baseline (569.728 us; speedup 1.0000x reference)
//
#include <hip/hip_runtime.h>
#include <hip/hip_bf16.h>
#include <cstdint>

#define NQ 22500
#define NV 13294
#define EMBED 256

// static level metadata (from setup_inputs): shapes [[100,100],[50,50],[25,25],[13,13]]
__device__ __forceinline__ int lvlH(int l) { return l==0?100 : l==1?50 : l==2?25 : 13; }
__device__ __forceinline__ int lvlW(int l) { return l==0?100 : l==1?50 : l==2?25 : 13; }
__device__ __forceinline__ int lvlStart(int l) { return l==0?0 : l==1?10000 : l==2?12500 : 13125; }

// ---------------------------------------------------------------------------
// Generic tiled f32 GEMM: C = A(MxK) @ B(KxN) + bias(N) [+ R(MxN) residual]
// 64x64 tile, BK=16, 256 threads, 4x4 microtile per thread.
// ---------------------------------------------------------------------------
template<bool RESID>
__global__ __launch_bounds__(256) void gemm64(
    const float* __restrict__ A, const float* __restrict__ B,
    const float* __restrict__ bias, const float* __restrict__ R,
    float* __restrict__ C, int M, int N, int K)
{
    __shared__ float As[16][64];
    __shared__ float Bs[16][64];
    const int tid  = threadIdx.x;
    const int row0 = blockIdx.x * 64;
    const int col0 = blockIdx.y * 64;
    const int tx = tid & 15, ty = tid >> 4;
    const int ar = tid >> 2, ak = (tid & 3) << 2;   // A tile: 64 rows x 16 k
    const int bk = tid >> 4, bc = (tid & 15) << 2;  // B tile: 16 k x 64 cols

    float acc[4][4] = {};

    for (int k0 = 0; k0 < K; k0 += 16) {
        float4 av;
        if (row0 + ar < M)
            av = *(const float4*)(A + (size_t)(row0 + ar) * K + k0 + ak);
        else
            av = make_float4(0.f, 0.f, 0.f, 0.f);
        float4 bv = *(const float4*)(B + (size_t)(k0 + bk) * N + col0 + bc);

        As[ak + 0][ar] = av.x;
        As[ak + 1][ar] = av.y;
        As[ak + 2][ar] = av.z;
        As[ak + 3][ar] = av.w;
        *(float4*)&Bs[bk][bc] = bv;
        __syncthreads();

#pragma unroll
        for (int k = 0; k < 16; ++k) {
            float4 a = *(const float4*)&As[k][ty << 2];
            float4 b = *(const float4*)&Bs[k][tx << 2];
            acc[0][0] += a.x * b.x; acc[0][1] += a.x * b.y; acc[0][2] += a.x * b.z; acc[0][3] += a.x * b.w;
            acc[1][0] += a.y * b.x; acc[1][1] += a.y * b.y; acc[1][2] += a.y * b.z; acc[1][3] += a.y * b.w;
            acc[2][0] += a.z * b.x; acc[2][1] += a.z * b.y; acc[2][2] += a.z * b.z; acc[2][3] += a.z * b.w;
            acc[3][0] += a.w * b.x; acc[3][1] += a.w * b.y; acc[3][2] += a.w * b.z; acc[3][3] += a.w * b.w;
        }
        __syncthreads();
    }

    const int col = col0 + (tx << 2);
    float4 bb = *(const float4*)(bias + col);
#pragma unroll
    for (int i = 0; i < 4; ++i) {
        int row = row0 + (ty << 2) + i;
        if (row < M) {
            float4 o;
            o.x = acc[i][0] + bb.x;
            o.y = acc[i][1] + bb.y;
            o.z = acc[i][2] + bb.z;
            o.w = acc[i][3] + bb.w;
            if (RESID) {
                float4 r = *(const float4*)(R + (size_t)row * N + col);
                o.x += r.x; o.y += r.y; o.z += r.z; o.w += r.w;
            }
            *(float4*)(C + (size_t)row * N + col) = o;
        }
    }
}

// ---------------------------------------------------------------------------
// Sampling kernel: one block per query. 256 threads = 8 heads x 32 lanes.
// Lane i (of its head's 32-lane group) precomputes location+weight for
// (l,p) = (i/8, i%8); softmax over 32 lanes via shfl_xor; then 32 broadcast
// iterations where each lane gathers its own channel c = lane.
// ---------------------------------------------------------------------------
__global__ __launch_bounds__(256) void sample_kernel(
    const float* __restrict__ v,        // (NV, 256)  col = h*32 + c
    const float* __restrict__ off_raw,  // (NQ, 512)  h*64 + l*16 + p*2 + {x,y}
    const float* __restrict__ attn_raw, // (NQ, 256)  h*32 + (l*8+p)
    const float* __restrict__ rp,       // (NQ, 4, 2)
    float* __restrict__ agg)            // (NQ, 256)
{
    const int q    = blockIdx.x;
    const int tid  = threadIdx.x;
    const int h    = tid >> 5;
    const int lane = tid & 31;
    const int l    = lane >> 3;
    const int p    = lane & 7;

    // per-lane (l,p) precompute
    const float ox = off_raw[(size_t)q * 512 + h * 64 + l * 16 + p * 2 + 0];
    const float oy = off_raw[(size_t)q * 512 + h * 64 + l * 16 + p * 2 + 1];
    const float rx = rp[(size_t)q * 8 + l * 2 + 0];
    const float ry = rp[(size_t)q * 8 + l * 2 + 1];
    const float Wl = (float)lvlW(l), Hl = (float)lvlH(l);
    // normalized loc -> pixel coords (align_corners=False)
    const float xf = (rx + ox / Wl) * Wl - 0.5f;
    const float yf = (ry + oy / Hl) * Hl - 0.5f;

    // softmax over the 32 (l,p) logits of this head
    float logit = attn_raw[(size_t)q * 256 + h * 32 + lane];
    float m = logit;
#pragma unroll
    for (int s = 16; s; s >>= 1) m = fmaxf(m, __shfl_xor(m, s, 32));
    float e = __expf(logit - m);
    float ssum = e;
#pragma unroll
    for (int s = 16; s; s >>= 1) ssum += __shfl_xor(ssum, s, 32);
    const float w = e / ssum;

    const int c = lane;  // channel owned by this lane during gather
    float acc = 0.f;

    for (int i = 0; i < 32; ++i) {
        const float xi = __shfl(xf, i, 32);
        const float yi = __shfl(yf, i, 32);
        const float wi = __shfl(w, i, 32);
        const int   li = i >> 3;
        const int   Wi = lvlW(li), Hi = lvlH(li);
        const int   base = lvlStart(li);

        const float x0f = floorf(xi), y0f = floorf(yi);
        const float fx = xi - x0f, fy = yi - y0f;
        const int x0 = (int)x0f, y0 = (int)y0f;
        const int x1 = x0 + 1, y1 = y0 + 1;

        auto g = [&](int yy, int xx) -> float {
            if ((unsigned)yy < (unsigned)Hi && (unsigned)xx < (unsigned)Wi)
                return v[(size_t)(base + yy * Wi + xx) * 256 + h * 32 + c];
            return 0.f;
        };
        const float v00 = g(y0, x0);
        const float v01 = g(y0, x1);
        const float v10 = g(y1, x0);
        const float v11 = g(y1, x1);

        acc += wi * ((1.f - fy) * ((1.f - fx) * v00 + fx * v01)
                   +        fy  * ((1.f - fx) * v10 + fx * v11));
    }

    agg[(size_t)q * 256 + tid] = acc;
}

// ---------------------------------------------------------------------------
extern "C" void kernel_launch(void* const* d_in, const int* in_sizes, int n_in,
                              void* d_out, int out_size, void* d_ws, size_t ws_size,
                              hipStream_t stream)
{
    const float* query   = (const float*)d_in[0];
    const float* value   = (const float*)d_in[1];
    const float* rp      = (const float*)d_in[2];
    // d_in[3] spatial_shapes, d_in[4] level_start_index: static, hardcoded
    const float* W_value = (const float*)d_in[5];
    const float* b_value = (const float*)d_in[6];
    const float* W_off   = (const float*)d_in[7];
    const float* b_off   = (const float*)d_in[8];
    const float* W_attn  = (const float*)d_in[9];
    const float* b_attn  = (const float*)d_in[10];
    const float* W_out   = (const float*)d_in[11];
    const float* b_out   = (const float*)d_in[12];
    float* out = (float*)d_out;

    float* ws      = (float*)d_ws;
    float* v_ws    = ws;                                  // NV*256
    float* off_ws  = v_ws   + (size_t)NV * 256;           // NQ*512
    float* attn_ws = off_ws + (size_t)NQ * 512;           // NQ*256
    float* agg_ws  = attn_ws + (size_t)NQ * 256;          // NQ*256

    dim3 blk(256);
    // value projection: (NV,256) @ (256,256)
    gemm64<false><<<dim3((NV + 63) / 64, 4), blk, 0, stream>>>(
        value, W_value, b_value, nullptr, v_ws, NV, 256, 256);
    // sampling offsets: (NQ,256) @ (256,512)
    gemm64<false><<<dim3((NQ + 63) / 64, 8), blk, 0, stream>>>(
        query, W_off, b_off, nullptr, off_ws, NQ, 512, 256);
    // attention logits: (NQ,256) @ (256,256)
    gemm64<false><<<dim3((NQ + 63) / 64, 4), blk, 0, stream>>>(
        query, W_attn, b_attn, nullptr, attn_ws, NQ, 256, 256);
    // bilinear sampling + weighted aggregation
    sample_kernel<<<NQ, 256, 0, stream>>>(v_ws, off_ws, attn_ws, rp, agg_ws);
    // output projection + residual: (NQ,256) @ (256,256) + b + query
    gemm64<true><<<dim3((NQ + 63) / 64, 4), blk, 0, stream>>>(
        agg_ws, W_out, b_out, query, out, NQ, 256, 256);
}

// Round 5
// 296.093 us; speedup vs baseline: 1.9242x; 1.9242x over previous
//
#include <hip/hip_runtime.h>
#include <hip/hip_bf16.h>
#include <cstdint>

#define NQ 22500
#define NV 13294
#define EMBED 256

typedef short bf16x8 __attribute__((ext_vector_type(8)));
typedef float f32x4  __attribute__((ext_vector_type(4)));

// static level metadata: shapes [[100,100],[50,50],[25,25],[13,13]]
__device__ __forceinline__ int lvlH(int l) { return l==0?100 : l==1?50 : l==2?25 : 13; }
__device__ __forceinline__ int lvlW(int l) { return l==0?100 : l==1?50 : l==2?25 : 13; }
__device__ __forceinline__ int lvlStart(int l) { return l==0?0 : l==1?10000 : l==2?12500 : 13125; }

// manual f32 -> bf16 round-to-nearest-even (no hip_bf16 API dependency)
__device__ __forceinline__ ushort f2bf(float x) {
    uint32_t u = __float_as_uint(x);
    uint32_t r = (u + 0x7FFFu + ((u >> 16) & 1u)) >> 16;
    return (ushort)r;
}

// ---------------------------------------------------------------------------
// prep: blockIdx.y selects job, grid-stride within.
//  y0: value f32 -> bf16 (contiguous, vec4)
//  y1: query f32 -> bf16 (contiguous, vec4)
//  y2..y5: W_value / W_off / W_attn / W_out -> bf16 transposed (N x K)
// ---------------------------------------------------------------------------
__global__ __launch_bounds__(256) void prep_kernel(
    const float* __restrict__ value, const float* __restrict__ query,
    const float* __restrict__ Wv, const float* __restrict__ Wo,
    const float* __restrict__ Wa, const float* __restrict__ Wt,
    ushort* __restrict__ val_bf, ushort* __restrict__ q_bf,
    ushort* __restrict__ Wv_t, ushort* __restrict__ Wo_t,
    ushort* __restrict__ Wa_t, ushort* __restrict__ Wt_t)
{
    const int y = blockIdx.y;
    const int idx0 = blockIdx.x * 256 + threadIdx.x;
    const int stride = gridDim.x * 256;

    if (y == 0) {
        for (int i = idx0; i < (NV * 256) / 4; i += stride) {
            float4 v = ((const float4*)value)[i];
            ushort4 o; o.x = f2bf(v.x); o.y = f2bf(v.y); o.z = f2bf(v.z); o.w = f2bf(v.w);
            ((ushort4*)val_bf)[i] = o;
        }
    } else if (y == 1) {
        for (int i = idx0; i < (NQ * 256) / 4; i += stride) {
            float4 v = ((const float4*)query)[i];
            ushort4 o; o.x = f2bf(v.x); o.y = f2bf(v.y); o.z = f2bf(v.z); o.w = f2bf(v.w);
            ((ushort4*)q_bf)[i] = o;
        }
    } else if (y == 2) {
        for (int i = idx0; i < 256 * 256; i += stride) {
            int n = i & 255, k = i >> 8;
            Wv_t[n * 256 + k] = f2bf(Wv[k * 256 + n]);
        }
    } else if (y == 3) {
        for (int i = idx0; i < 512 * 256; i += stride) {
            int n = i & 511, k = i >> 9;
            Wo_t[n * 256 + k] = f2bf(Wo[k * 512 + n]);
        }
    } else if (y == 4) {
        for (int i = idx0; i < 256 * 256; i += stride) {
            int n = i & 255, k = i >> 8;
            Wa_t[n * 256 + k] = f2bf(Wa[k * 256 + n]);
        }
    } else {
        for (int i = idx0; i < 256 * 256; i += stride) {
            int n = i & 255, k = i >> 8;
            Wt_t[n * 256 + k] = f2bf(Wt[k * 256 + n]);
        }
    }
}

// ---------------------------------------------------------------------------
// bf16 MFMA GEMM: C(MxN f32) = A(Mx256 bf16) @ Bt(Nx256 bf16)^T + bias [+ R]
// 64x64 tile, 4 waves (2x2), each wave 32x32 via 2x2 16x16x32 MFMA frags.
// LDS rows padded to 40 ushorts (80 B): 2-way banks only, 16B-aligned b128.
// ---------------------------------------------------------------------------
template<bool RESID>
__global__ __launch_bounds__(256) void gemm_bf16(
    const ushort* __restrict__ A,   // M x 256, row-major bf16
    const ushort* __restrict__ Bt,  // N x 256, row-major bf16 (pre-transposed)
    const float* __restrict__ bias, const float* __restrict__ R,
    float* __restrict__ C, int M, int N)
{
    __shared__ __align__(16) ushort As[64][40];
    __shared__ __align__(16) ushort Bs[64][40];

    const int tid  = threadIdx.x;
    const int row0 = blockIdx.x * 64;
    const int col0 = blockIdx.y * 64;
    const int wave = tid >> 6, lane = tid & 63;
    const int wm = wave >> 1, wn = wave & 1;
    const int r = lane & 15, g = lane >> 4;
    const int sr = tid >> 2, sc = tid & 3;      // staging: row, 8-elem col group

    f32x4 acc[2][2] = {};

    const int arow = row0 + sr;
    const bool aok = arow < M;
    const ushort* Aptr = A + (size_t)arow * 256 + sc * 8;
    const ushort* Bptr = Bt + (size_t)(col0 + sr) * 256 + sc * 8;

    for (int k0 = 0; k0 < 256; k0 += 32) {
        uint4 av = aok ? *(const uint4*)(Aptr + k0) : make_uint4(0, 0, 0, 0);
        uint4 bv = *(const uint4*)(Bptr + k0);
        *(uint4*)&As[sr][sc * 8] = av;
        *(uint4*)&Bs[sr][sc * 8] = bv;
        __syncthreads();

        bf16x8 af0 = *(const bf16x8*)&As[wm * 32 + r][g * 8];
        bf16x8 af1 = *(const bf16x8*)&As[wm * 32 + 16 + r][g * 8];
        bf16x8 bf0 = *(const bf16x8*)&Bs[wn * 32 + r][g * 8];
        bf16x8 bf1 = *(const bf16x8*)&Bs[wn * 32 + 16 + r][g * 8];

        acc[0][0] = __builtin_amdgcn_mfma_f32_16x16x32_bf16(af0, bf0, acc[0][0], 0, 0, 0);
        acc[0][1] = __builtin_amdgcn_mfma_f32_16x16x32_bf16(af0, bf1, acc[0][1], 0, 0, 0);
        acc[1][0] = __builtin_amdgcn_mfma_f32_16x16x32_bf16(af1, bf0, acc[1][0], 0, 0, 0);
        acc[1][1] = __builtin_amdgcn_mfma_f32_16x16x32_bf16(af1, bf1, acc[1][1], 0, 0, 0);
        __syncthreads();
    }

    // epilogue: C/D layout (verified m89/m91): col = lane&15, row = (lane>>4)*4 + j
#pragma unroll
    for (int mi = 0; mi < 2; ++mi)
#pragma unroll
        for (int ni = 0; ni < 2; ++ni) {
            const int col = col0 + wn * 32 + ni * 16 + r;
            const float bb = bias[col];
#pragma unroll
            for (int j = 0; j < 4; ++j) {
                const int row = row0 + wm * 32 + mi * 16 + g * 4 + j;
                if (row < M) {
                    float o = acc[mi][ni][j] + bb;
                    if (RESID) o += R[(size_t)row * N + col];
                    C[(size_t)row * N + col] = o;
                }
            }
        }
}

// ---------------------------------------------------------------------------
// Sampling kernel v2: one block per query, 256 threads = 8 heads x 32 lanes.
// Phase 1: lane s (= l*8+p) computes softmax weight, 4 clamped corner row
//          indices and 4 pre-multiplied bilinear weights -> LDS.
// Phase 2: 32 lanes/head = 4 sample-slots x 8 channel-groups; float4 corner
//          gathers, 16 FMA/iter, 8 iters; 2x shfl_xor reduce; bf16 store.
// ---------------------------------------------------------------------------
__global__ __launch_bounds__(256) void sample_kernel(
    const float* __restrict__ v,        // (NV, 256) f32, col = h*32 + c
    const float* __restrict__ off_raw,  // (NQ, 512)  h*64 + l*16 + p*2 + {x,y}
    const float* __restrict__ attn_raw, // (NQ, 256)  h*32 + (l*8+p)
    const float* __restrict__ rp,       // (NQ, 4, 2)
    ushort* __restrict__ agg)           // (NQ, 256) bf16
{
    __shared__ int4   idxs[8][32];
    __shared__ float4 wts[8][32];

    const int q    = blockIdx.x;
    const int tid  = threadIdx.x;
    const int h    = tid >> 5;
    const int lane = tid & 31;
    const int l    = lane >> 3;
    const int p    = lane & 7;

    // ---- Phase 1 ----
    const float ox = off_raw[(size_t)q * 512 + h * 64 + l * 16 + p * 2 + 0];
    const float oy = off_raw[(size_t)q * 512 + h * 64 + l * 16 + p * 2 + 1];
    const float rx = rp[(size_t)q * 8 + l * 2 + 0];
    const float ry = rp[(size_t)q * 8 + l * 2 + 1];
    const float Wl = (float)lvlW(l), Hl = (float)lvlH(l);
    const int   Wi = lvlW(l), Hi = lvlH(l), base = lvlStart(l);
    const float xf = rx * Wl + ox - 0.5f;
    const float yf = ry * Hl + oy - 0.5f;

    float logit = attn_raw[(size_t)q * 256 + h * 32 + lane];
    float m = logit;
#pragma unroll
    for (int s = 16; s; s >>= 1) m = fmaxf(m, __shfl_xor(m, s, 32));
    float e = __expf(logit - m);
    float ssum = e;
#pragma unroll
    for (int s = 16; s; s >>= 1) ssum += __shfl_xor(ssum, s, 32);
    const float w = e / ssum;

    const float x0f = floorf(xf), y0f = floorf(yf);
    const float fx = xf - x0f, fy = yf - y0f;
    const int x0 = (int)x0f, y0 = (int)y0f;
    const int x1 = x0 + 1, y1 = y0 + 1;

    const bool vx0 = (unsigned)x0 < (unsigned)Wi;
    const bool vx1 = (unsigned)x1 < (unsigned)Wi;
    const bool vy0 = (unsigned)y0 < (unsigned)Hi;
    const bool vy1 = (unsigned)y1 < (unsigned)Hi;
    const int cx0 = vx0 ? x0 : 0, cx1 = vx1 ? x1 : 0;
    const int cy0 = vy0 ? y0 : 0, cy1 = vy1 ? y1 : 0;

    int4 idx;
    idx.x = base + cy0 * Wi + cx0;
    idx.y = base + cy0 * Wi + cx1;
    idx.z = base + cy1 * Wi + cx0;
    idx.w = base + cy1 * Wi + cx1;
    float4 wv;
    wv.x = (vy0 && vx0) ? w * (1.f - fy) * (1.f - fx) : 0.f;
    wv.y = (vy0 && vx1) ? w * (1.f - fy) * fx         : 0.f;
    wv.z = (vy1 && vx0) ? w * fy * (1.f - fx)         : 0.f;
    wv.w = (vy1 && vx1) ? w * fy * fx                 : 0.f;

    idxs[h][lane] = idx;
    wts[h][lane]  = wv;
    __syncthreads();

    // ---- Phase 2 ----
    const int slot = lane >> 3;           // 4 sample-slots
    const int cg   = lane & 7;            // channel group (4 ch)
    const float* vbase = v + h * 32 + cg * 4;

    float4 acc = make_float4(0.f, 0.f, 0.f, 0.f);
#pragma unroll
    for (int i = 0; i < 8; ++i) {
        const int s = slot * 8 + i;
        const int4   id = idxs[h][s];
        const float4 ww = wts[h][s];
        const float4 v00 = *(const float4*)(vbase + (size_t)id.x * 256);
        const float4 v01 = *(const float4*)(vbase + (size_t)id.y * 256);
        const float4 v10 = *(const float4*)(vbase + (size_t)id.z * 256);
        const float4 v11 = *(const float4*)(vbase + (size_t)id.w * 256);
        acc.x += ww.x * v00.x + ww.y * v01.x + ww.z * v10.x + ww.w * v11.x;
        acc.y += ww.x * v00.y + ww.y * v01.y + ww.z * v10.y + ww.w * v11.y;
        acc.z += ww.x * v00.z + ww.y * v01.z + ww.z * v10.z + ww.w * v11.z;
        acc.w += ww.x * v00.w + ww.y * v01.w + ww.z * v10.w + ww.w * v11.w;
    }

#pragma unroll
    for (int s = 8; s <= 16; s <<= 1) {
        acc.x += __shfl_xor(acc.x, s, 32);
        acc.y += __shfl_xor(acc.y, s, 32);
        acc.z += __shfl_xor(acc.z, s, 32);
        acc.w += __shfl_xor(acc.w, s, 32);
    }

    if (slot == 0) {
        ushort4 pk;
        pk.x = f2bf(acc.x); pk.y = f2bf(acc.y); pk.z = f2bf(acc.z); pk.w = f2bf(acc.w);
        *(ushort4*)(agg + (size_t)q * 256 + h * 32 + cg * 4) = pk;
    }
}

// ---------------------------------------------------------------------------
extern "C" void kernel_launch(void* const* d_in, const int* in_sizes, int n_in,
                              void* d_out, int out_size, void* d_ws, size_t ws_size,
                              hipStream_t stream)
{
    const float* query   = (const float*)d_in[0];
    const float* value   = (const float*)d_in[1];
    const float* rp      = (const float*)d_in[2];
    // d_in[3] spatial_shapes, d_in[4] level_start_index: static, hardcoded
    const float* W_value = (const float*)d_in[5];
    const float* b_value = (const float*)d_in[6];
    const float* W_off   = (const float*)d_in[7];
    const float* b_off   = (const float*)d_in[8];
    const float* W_attn  = (const float*)d_in[9];
    const float* b_attn  = (const float*)d_in[10];
    const float* W_out   = (const float*)d_in[11];
    const float* b_out   = (const float*)d_in[12];
    float* out = (float*)d_out;

    // workspace layout (~103.6 MB; R1 run proved ws_size >= ~106 MB)
    float*  v_ws    = (float*)d_ws;                      // NV*256 f32
    float*  off_ws  = v_ws + (size_t)NV * 256;           // NQ*512 f32
    float*  attn_ws = off_ws + (size_t)NQ * 512;         // NQ*256 f32
    ushort* q_bf    = (ushort*)(attn_ws + (size_t)NQ * 256); // NQ*256 bf16
    ushort* val_bf  = q_bf + (size_t)NQ * 256;           // NV*256 bf16
    ushort* Wv_t    = val_bf + (size_t)NV * 256;         // 256*256
    ushort* Wo_t    = Wv_t + 256 * 256;                  // 512*256
    ushort* Wa_t    = Wo_t + 512 * 256;                  // 256*256
    ushort* Wt_t    = Wa_t + 256 * 256;                  // 256*256
    ushort* agg_bf  = q_bf;   // alias: q_bf dead after attn GEMM, reused as agg

    dim3 blk(256);

    prep_kernel<<<dim3(2048, 6), blk, 0, stream>>>(
        value, query, W_value, W_off, W_attn, W_out,
        val_bf, q_bf, Wv_t, Wo_t, Wa_t, Wt_t);

    // value projection: (NV,256) @ (256,256) -> f32
    gemm_bf16<false><<<dim3((NV + 63) / 64, 4), blk, 0, stream>>>(
        val_bf, Wv_t, b_value, nullptr, v_ws, NV, 256);
    // sampling offsets: (NQ,256) @ (256,512) -> f32
    gemm_bf16<false><<<dim3((NQ + 63) / 64, 8), blk, 0, stream>>>(
        q_bf, Wo_t, b_off, nullptr, off_ws, NQ, 512);
    // attention logits: (NQ,256) @ (256,256) -> f32
    gemm_bf16<false><<<dim3((NQ + 63) / 64, 4), blk, 0, stream>>>(
        q_bf, Wa_t, b_attn, nullptr, attn_ws, NQ, 256);
    // bilinear sampling + weighted aggregation -> bf16 agg (reuses q_bf)
    sample_kernel<<<NQ, blk, 0, stream>>>(v_ws, off_ws, attn_ws, rp, agg_bf);
    // output projection + residual: (NQ,256) @ (256,256) + b + query
    gemm_bf16<true><<<dim3((NQ + 63) / 64, 4), blk, 0, stream>>>(
        agg_bf, Wt_t, b_out, query, out, NQ, 256);
}